// Round 19
// baseline (304.995 us; speedup 1.0000x reference)
//
#include <hip/hip_runtime.h>

// Problem shapes (fixed by reference setup_inputs)
#define B_DIM 1024
#define C_DIM 128
#define K_DIM 1024
#define E_DIM 4
#define EMBED_ELEMS (B_DIM * C_DIM * E_DIM)
#define NROWS (B_DIM * C_DIM)

typedef float f32x4 __attribute__((ext_vector_type(4)));

// f32 screen: worst-case |d32 - d64| <= ~1e-4; order flip needs f32 gap
// <= 2e-4. THR = 1e-3 gives 5x margin (absmax 0.0 in R15-R18).
#define SCREEN_THR 1e-3f

// d_ws layout: [0] = atomic counter; +4 KB: idx[NROWS]; then list[NROWS].
#define WS_IDX_OFF 1024          // in ints
#define WS_LIST_OFF (1024 + NROWS)

__global__ void vq_init(int* ws) { ws[0] = 0; }

// ---------------------------------------------------------------------------
// K_screen: f32 top-2 argmin, register-cached codebook, NO zero stores.
// Grid = 4096 blocks. Writes embed + idx + fixup list (~1% rows).
// ---------------------------------------------------------------------------
__global__ __launch_bounds__(256) void vq_screen_kernel(
    const float* __restrict__ cw_q,      // (B, C*E) f32
    const float* __restrict__ codebook,  // (C, K, E) f32
    float* __restrict__ out,             // [embed | one_hot]
    int* __restrict__ ws)                // counter / idx / list
{
    const int bid  = blockIdx.x;
    const int lane = threadIdx.x & 63;
    const int wave = threadIdx.x >> 6;
    const int c      = bid >> 5;         // 32 blocks per c
    const int btile  = bid & 31;
    const int b_base = btile * 32 + wave * 8;

    const float4* cb4 = (const float4*)codebook + (size_t)c * K_DIM;
    const float4* x4  = (const float4*)cw_q;    // (B, C) float4
    float4* emb4 = (float4*)out;                // (B, C) float4
    int* idx_out = ws + WS_IDX_OFF;
    int* list    = ws + WS_LIST_OFF;

    // Register-cache this c's codebook: lane owns k = j*64+lane.
    float4 cb[16];
#pragma unroll
    for (int j = 0; j < 16; ++j)
        cb[j] = cb4[j * 64 + lane];

    float bsqf[16];
#pragma unroll
    for (int j = 0; j < 16; ++j)
        bsqf[j] = cb[j].x * cb[j].x + cb[j].y * cb[j].y
                + cb[j].z * cb[j].z + cb[j].w * cb[j].w;

    for (int g = 0; g < 2; ++g) {
        float x2f[4][4];
#pragma unroll
        for (int ii = 0; ii < 4; ++ii) {
            const float4 x = x4[(size_t)(b_base + g * 4 + ii) * C_DIM + c];
            x2f[ii][0] = -2.0f * x.x;  x2f[ii][1] = -2.0f * x.y;
            x2f[ii][2] = -2.0f * x.z;  x2f[ii][3] = -2.0f * x.w;
        }

        float b1[4], b2[4];  int k1[4];
#pragma unroll
        for (int ii = 0; ii < 4; ++ii) { b1[ii] = INFINITY; b2[ii] = INFINITY; k1[ii] = 0x7fffffff; }

#pragma unroll
        for (int j = 0; j < 16; ++j) {
            const float bsqj = bsqf[j];
            const int k = j * 64 + lane;
#pragma unroll
            for (int ii = 0; ii < 4; ++ii) {
                const float d = fmaf(cb[j].w, x2f[ii][3],
                                fmaf(cb[j].z, x2f[ii][2],
                                fmaf(cb[j].y, x2f[ii][1],
                                fmaf(cb[j].x, x2f[ii][0], bsqj))));
                const bool  lt1  = d < b1[ii];
                const float old1 = b1[ii];
                b1[ii] = lt1 ? d : old1;
                k1[ii] = lt1 ? k : k1[ii];
                b2[ii] = lt1 ? old1 : fminf(b2[ii], d);
            }
        }

        // Butterfly: global top-2 values + argmin index (32-bit ops).
#pragma unroll
        for (int off = 32; off >= 1; off >>= 1) {
#pragma unroll
            for (int ii = 0; ii < 4; ++ii) {
                const float ob1 = __shfl_xor(b1[ii], off);
                const int   ok1 = __shfl_xor(k1[ii], off);
                const float ob2 = __shfl_xor(b2[ii], off);
                const float mx  = fmaxf(b1[ii], ob1);
                b2[ii] = fminf(mx, fminf(b2[ii], ob2));
                if (ob1 < b1[ii] || (ob1 == b1[ii] && ok1 < k1[ii])) {
                    b1[ii] = ob1; k1[ii] = ok1;
                }
            }
        }

        // Provisional writes; ambiguous rows -> fixup list (~1%).
#pragma unroll
        for (int ii = 0; ii < 4; ++ii) {
            const int b  = b_base + g * 4 + ii;
            const int fk = k1[ii];
            const int r  = b * C_DIM + c;
            if (lane == 0) {
                emb4[r]    = cb4[fk];   // L2-hit gather
                idx_out[r] = fk;
                if (!(b2[ii] - b1[ii] > SCREEN_THR)) {
                    const int p = atomicAdd(ws, 1);
                    list[p] = r;
                }
            }
        }
    }
}

// ---------------------------------------------------------------------------
// K_zero: fill-shaped dedicated zero kernel. 512 blocks (2/CU), each writes
// a 1 MB CONTIGUOUS slab: thread t stores f32x4 at slab + q*256 + t,
// q = 0..255 (4 KB steps), unroll 8. Few, long, contiguous streams.
// ---------------------------------------------------------------------------
__global__ __launch_bounds__(256) void vq_zero_kernel(float* __restrict__ out)
{
    f32x4* dst = (f32x4*)(out + EMBED_ELEMS)
               + (size_t)blockIdx.x * 65536 + threadIdx.x;
    const f32x4 z = {0.f, 0.f, 0.f, 0.f};
#pragma unroll 8
    for (int q = 0; q < 256; ++q)
        dst[q * 256] = z;
}

// ---------------------------------------------------------------------------
// K_fix: exact f64 re-solve for flagged rows (R3-proven path). One wave/row.
// ---------------------------------------------------------------------------
__global__ __launch_bounds__(256) void vq_fix_kernel(
    const float* __restrict__ cw_q,
    const float* __restrict__ codebook,
    float* __restrict__ out,
    int* __restrict__ ws)
{
    const int lane = threadIdx.x & 63;
    const int wave = threadIdx.x >> 6;
    const int n    = ws[0];
    const int* list = ws + WS_LIST_OFF;
    int* idx_out    = ws + WS_IDX_OFF;
    const float4* x4 = (const float4*)cw_q;
    float4* emb4     = (float4*)out;

    for (int w = blockIdx.x * 4 + wave; w < n; w += gridDim.x * 4) {
        const int r = list[w];
        const int c = r & (C_DIM - 1);
        const float4* cb4 = (const float4*)codebook + (size_t)c * K_DIM;

        const float4 x = x4[r];
        const double x20 = -2.0 * (double)x.x;
        const double x21 = -2.0 * (double)x.y;
        const double x22 = -2.0 * (double)x.z;
        const double x23 = -2.0 * (double)x.w;

        double bd = INFINITY;  int bk = 0x7fffffff;
        for (int j = 0; j < 16; ++j) {
            const float4 cb = cb4[j * 64 + lane];
            const double bx = (double)cb.x, by = (double)cb.y,
                         bz = (double)cb.z, bw = (double)cb.w;
            const double bsqj = bx * bx + by * by + bz * bz + bw * bw;
            const double d = fma(bw, x23, fma(bz, x22,
                             fma(by, x21, fma(bx, x20, bsqj))));
            const int k = j * 64 + lane;
            if (d < bd) { bd = d; bk = k; }
        }
#pragma unroll
        for (int off = 32; off >= 1; off >>= 1) {
            const double od = __shfl_xor(bd, off);
            const int    oi = __shfl_xor(bk, off);
            if (od < bd || (od == bd && oi < bk)) { bd = od; bk = oi; }
        }
        if (lane == 0) {
            emb4[r]    = cb4[bk];
            idx_out[r] = bk;
        }
    }
}

// ---------------------------------------------------------------------------
// K_ones: scatter the 131072 ones (reads final idx, after K_fix).
// ---------------------------------------------------------------------------
__global__ __launch_bounds__(256) void vq_scatter_ones(
    const int* __restrict__ ws,
    float* __restrict__ out)
{
    const int r = blockIdx.x * 256 + threadIdx.x;
    const int k = (ws + WS_IDX_OFF)[r];
    out[EMBED_ELEMS + (size_t)r * K_DIM + k] = 1.0f;
}

extern "C" void kernel_launch(void* const* d_in, const int* in_sizes, int n_in,
                              void* d_out, int out_size, void* d_ws, size_t ws_size,
                              hipStream_t stream) {
    const float* cw_q     = (const float*)d_in[0];
    const float* codebook = (const float*)d_in[1];
    float* out = (float*)d_out;
    int*   ws  = (int*)d_ws;

    vq_init<<<1, 1, 0, stream>>>(ws);
    vq_screen_kernel<<<C_DIM * (B_DIM / 32), 256, 0, stream>>>(cw_q, codebook, out, ws);
    vq_zero_kernel<<<512, 256, 0, stream>>>(out);
    vq_fix_kernel<<<256, 256, 0, stream>>>(cw_q, codebook, out, ws);
    vq_scatter_ones<<<NROWS / 256, 256, 0, stream>>>(ws, out);
}

// Round 20
// 168.925 us; speedup vs baseline: 1.8055x; 1.8055x over previous
//
#include <hip/hip_runtime.h>

// Problem shapes (fixed by reference setup_inputs)
#define B_DIM 1024
#define C_DIM 128
#define K_DIM 1024
#define E_DIM 4
#define EMBED_ELEMS (B_DIM * C_DIM * E_DIM)
#define NROWS (B_DIM * C_DIM)

typedef float f32x4 __attribute__((ext_vector_type(4)));

// f32 screen: worst-case |d32 - d64| <= ~1e-4; order flip needs f32 gap
// <= 2e-4. THR = 1e-3 gives 5x margin (absmax 0.0 in R15-R19).
#define SCREEN_THR 1e-3f

// d_ws layout: [0] = atomic counter; +4 KB: idx[NROWS]; then list[NROWS].
#define WS_IDX_OFF 1024          // in ints
#define WS_LIST_OFF (1024 + NROWS)

// Grid-stride paced zeros: slot s covers a 16 MB stripe; within a stripe,
// block bid owns a 4 KB chunk. 32 slots x 16 MB = 512 MB.
#define SLOT_F32X4 (4096 * 256)  // f32x4 elements per stripe = 16 MB

__global__ void vq_init(int* ws) { ws[0] = 0; }

// ---------------------------------------------------------------------------
// K_screen: f32 top-2 screen (LDS codebook) + paced GRID-STRIDE zero stores
// (1 per j-iteration, 32 slots) + embed/idx + fixup list.
// Grid = 4096 blocks.
// ---------------------------------------------------------------------------
__global__ __launch_bounds__(256) void vq_screen_kernel(
    const float* __restrict__ cw_q,      // (B, C*E) f32
    const float* __restrict__ codebook,  // (C, K, E) f32
    float* __restrict__ out,             // [embed | one_hot]
    int* __restrict__ ws)                // counter / idx / list
{
    __shared__ float4 lds_cb[K_DIM];     // 16 KB: codebook[c]

    const int lane = threadIdx.x & 63;
    const int wave = threadIdx.x >> 6;
    const int bid  = blockIdx.x;
    const int c      = bid >> 5;         // 32 blocks per c
    const int btile  = bid & 31;
    const int b_base = btile * 32 + wave * 8;

    const float4* cb4 = (const float4*)codebook + (size_t)c * K_DIM;
    const float4* x4  = (const float4*)cw_q;    // (B, C) float4
    float4* emb4 = (float4*)out;                // (B, C) float4
    int* idx_out = ws + WS_IDX_OFF;
    int* list    = ws + WS_LIST_OFF;

    // Grid-stride zero base: this block's 4 KB chunk within each stripe.
    f32x4* zbase = (f32x4*)(out + EMBED_ELEMS) + (size_t)bid * 256
                 + threadIdx.x;
    const f32x4 zval = {0.f, 0.f, 0.f, 0.f};

    for (int t = threadIdx.x; t < K_DIM; t += 256)
        lds_cb[t] = cb4[t];
    float4 xr[8];
#pragma unroll
    for (int i = 0; i < 8; ++i)
        xr[i] = x4[(size_t)(b_base + i) * C_DIM + c];
    __syncthreads();

    // Per-lane ||b_k||^2 in f32, hoisted.
    float bsqf[16];
#pragma unroll
    for (int j = 0; j < 16; ++j) {
        const float4 cb = lds_cb[j * 64 + lane];
        bsqf[j] = cb.x * cb.x + cb.y * cb.y + cb.z * cb.z + cb.w * cb.w;
    }

    for (int g = 0; g < 2; ++g) {
        float x2f[4][4];
#pragma unroll
        for (int ii = 0; ii < 4; ++ii) {
            const float4 x = xr[g * 4 + ii];
            x2f[ii][0] = -2.0f * x.x;  x2f[ii][1] = -2.0f * x.y;
            x2f[ii][2] = -2.0f * x.z;  x2f[ii][3] = -2.0f * x.w;
        }

        float b1[4], b2[4];  int k1[4];
#pragma unroll
        for (int ii = 0; ii < 4; ++ii) { b1[ii] = INFINITY; b2[ii] = INFINITY; k1[ii] = 0x7fffffff; }

        float4 cbn = lds_cb[lane];
#pragma unroll 1   // keep one store per iteration — do NOT re-cluster
        for (int j = 0; j < 16; ++j) {
            const float4 cb = cbn;
            if (j < 15) cbn = lds_cb[(j + 1) * 64 + lane];
            // paced GRID-STRIDE zero store: stripe g*16+j
            zbase[(size_t)(g * 16 + j) * SLOT_F32X4] = zval;

            const float bsqj = bsqf[j];
            const int k = j * 64 + lane;
#pragma unroll
            for (int ii = 0; ii < 4; ++ii) {
                const float d = fmaf(cb.w, x2f[ii][3],
                                fmaf(cb.z, x2f[ii][2],
                                fmaf(cb.y, x2f[ii][1],
                                fmaf(cb.x, x2f[ii][0], bsqj))));
                const bool  lt1  = d < b1[ii];
                const float old1 = b1[ii];
                b1[ii] = lt1 ? d : old1;
                k1[ii] = lt1 ? k : k1[ii];
                b2[ii] = lt1 ? old1 : fminf(b2[ii], d);
            }
        }

        // Butterfly: global top-2 values + argmin index (32-bit ops).
#pragma unroll
        for (int off = 32; off >= 1; off >>= 1) {
#pragma unroll
            for (int ii = 0; ii < 4; ++ii) {
                const float ob1 = __shfl_xor(b1[ii], off);
                const int   ok1 = __shfl_xor(k1[ii], off);
                const float ob2 = __shfl_xor(b2[ii], off);
                const float mx  = fmaxf(b1[ii], ob1);
                b2[ii] = fminf(mx, fminf(b2[ii], ob2));
                if (ob1 < b1[ii] || (ob1 == b1[ii] && ok1 < k1[ii])) {
                    b1[ii] = ob1; k1[ii] = ok1;
                }
            }
        }

        // Provisional writes; ambiguous rows -> fixup list (~1%).
#pragma unroll
        for (int ii = 0; ii < 4; ++ii) {
            const int b  = b_base + g * 4 + ii;
            const int fk = k1[ii];
            const int r  = b * C_DIM + c;
            if (lane == 0) {
                emb4[r]    = lds_cb[fk];
                idx_out[r] = fk;
                if (!(b2[ii] - b1[ii] > SCREEN_THR)) {
                    const int p = atomicAdd(ws, 1);
                    list[p] = r;
                }
            }
        }
    }
}

// ---------------------------------------------------------------------------
// K_fix: exact f64 re-solve for flagged rows (R3-proven path). One wave/row.
// ---------------------------------------------------------------------------
__global__ __launch_bounds__(256) void vq_fix_kernel(
    const float* __restrict__ cw_q,
    const float* __restrict__ codebook,
    float* __restrict__ out,
    int* __restrict__ ws)
{
    const int lane = threadIdx.x & 63;
    const int wave = threadIdx.x >> 6;
    const int n    = ws[0];
    const int* list = ws + WS_LIST_OFF;
    int* idx_out    = ws + WS_IDX_OFF;
    const float4* x4 = (const float4*)cw_q;
    float4* emb4     = (float4*)out;

    for (int w = blockIdx.x * 4 + wave; w < n; w += gridDim.x * 4) {
        const int r = list[w];
        const int c = r & (C_DIM - 1);
        const float4* cb4 = (const float4*)codebook + (size_t)c * K_DIM;

        const float4 x = x4[r];
        const double x20 = -2.0 * (double)x.x;
        const double x21 = -2.0 * (double)x.y;
        const double x22 = -2.0 * (double)x.z;
        const double x23 = -2.0 * (double)x.w;

        double bd = INFINITY;  int bk = 0x7fffffff;
        for (int j = 0; j < 16; ++j) {
            const float4 cb = cb4[j * 64 + lane];
            const double bx = (double)cb.x, by = (double)cb.y,
                         bz = (double)cb.z, bw = (double)cb.w;
            const double bsqj = bx * bx + by * by + bz * bz + bw * bw;
            const double d = fma(bw, x23, fma(bz, x22,
                             fma(by, x21, fma(bx, x20, bsqj))));
            const int k = j * 64 + lane;
            if (d < bd) { bd = d; bk = k; }
        }
#pragma unroll
        for (int off = 32; off >= 1; off >>= 1) {
            const double od = __shfl_xor(bd, off);
            const int    oi = __shfl_xor(bk, off);
            if (od < bd || (od == bd && oi < bk)) { bd = od; bk = oi; }
        }
        if (lane == 0) {
            emb4[r]    = cb4[bk];
            idx_out[r] = bk;
        }
    }
}

// ---------------------------------------------------------------------------
// K_ones: scatter the 131072 ones (reads final idx, after K_fix).
// ---------------------------------------------------------------------------
__global__ __launch_bounds__(256) void vq_scatter_ones(
    const int* __restrict__ ws,
    float* __restrict__ out)
{
    const int r = blockIdx.x * 256 + threadIdx.x;
    const int k = (ws + WS_IDX_OFF)[r];
    out[EMBED_ELEMS + (size_t)r * K_DIM + k] = 1.0f;
}

extern "C" void kernel_launch(void* const* d_in, const int* in_sizes, int n_in,
                              void* d_out, int out_size, void* d_ws, size_t ws_size,
                              hipStream_t stream) {
    const float* cw_q     = (const float*)d_in[0];
    const float* codebook = (const float*)d_in[1];
    float* out = (float*)d_out;
    int*   ws  = (int*)d_ws;

    vq_init<<<1, 1, 0, stream>>>(ws);
    vq_screen_kernel<<<C_DIM * (B_DIM / 32), 256, 0, stream>>>(cw_q, codebook, out, ws);
    vq_fix_kernel<<<256, 256, 0, stream>>>(cw_q, codebook, out, ws);
    vq_scatter_ones<<<NROWS / 256, 256, 0, stream>>>(ws, out);
}

// Round 21
// 131.221 us; speedup vs baseline: 2.3243x; 1.2873x over previous
//
#include <hip/hip_runtime.h>

// Problem shapes (fixed by reference setup_inputs)
#define B_DIM 1024
#define C_DIM 128
#define K_DIM 1024
#define E_DIM 4
#define EMBED_ELEMS (B_DIM * C_DIM * E_DIM)
#define NROWS (B_DIM * C_DIM)

typedef float f32x4 __attribute__((ext_vector_type(4)));

// d_ws layout: idx[NROWS] at offset 0 (every element written every call).
// ---------------------------------------------------------------------------
// K_fused: exact-f64 argmin (R3-proven ordering) + embed/idx + paced zero
// fill. 2048 blocks x 256 KB slab each = ONE resident cohort (8 blocks/CU),
// no block turnover. Each of 4 waves owns 16 rows (4 groups of 4); the
// 4x16 = 64 j-iterations each carry exactly one f32x4 zero store
// (64 x 4 KB = 256 KB). Store-issue stays rate-matched to drain (R13's
// proven pacing); compute is free underneath it.
// ---------------------------------------------------------------------------
__global__ __launch_bounds__(256) void vq_fused_kernel(
    const float* __restrict__ cw_q,      // (B, C*E) f32
    const float* __restrict__ codebook,  // (C, K, E) f32
    float* __restrict__ out,             // [embed | one_hot]
    int* __restrict__ idx_out)           // (B, C) int32 in d_ws
{
    __shared__ float4 lds_cb[K_DIM];     // 16 KB: codebook[c]

    const int lane = threadIdx.x & 63;
    const int wave = threadIdx.x >> 6;
    const int bid  = blockIdx.x;
    const int c      = bid >> 4;         // 16 blocks per c
    const int btile  = bid & 15;
    const int b_base = btile * 64 + wave * 16;

    const float4* cb4 = (const float4*)codebook + (size_t)c * K_DIM;
    const float4* x4  = (const float4*)cw_q;    // (B, C) float4
    float4* emb4 = (float4*)out;                // (B, C) float4

    // Zero-fill destination: 256 KB contiguous slab per block.
    f32x4* zdst = (f32x4*)(out + EMBED_ELEMS) + (size_t)bid * 16384
                + threadIdx.x;
    const f32x4 zval = {0.f, 0.f, 0.f, 0.f};

    // Stage codebook into LDS (once per block for 64 rows).
    for (int t = threadIdx.x; t < K_DIM; t += 256)
        lds_cb[t] = cb4[t];
    __syncthreads();

    // ||b_k||^2 in f64 (exact from f32 inputs -> true ordering, R3-proven).
    double bsq[16];
#pragma unroll
    for (int j = 0; j < 16; ++j) {
        const float4 cb = lds_cb[j * 64 + lane];
        const double bx = (double)cb.x, by = (double)cb.y,
                     bz = (double)cb.z, bw = (double)cb.w;
        bsq[j] = bx * bx + by * by + bz * bz + bw * bw;
    }

    // 4 groups of 4 rows; one paced zero store per j-iteration (64 slots).
    for (int g = 0; g < 4; ++g) {
        double x2[4][4];
#pragma unroll
        for (int ii = 0; ii < 4; ++ii) {
            const float4 x = x4[(size_t)(b_base + g * 4 + ii) * C_DIM + c];
            x2[ii][0] = -2.0 * (double)x.x;
            x2[ii][1] = -2.0 * (double)x.y;
            x2[ii][2] = -2.0 * (double)x.z;
            x2[ii][3] = -2.0 * (double)x.w;
        }

        double bestd[4];
        int    bestk[4];
#pragma unroll
        for (int ii = 0; ii < 4; ++ii) { bestd[ii] = INFINITY; bestk[ii] = 0x7fffffff; }

#pragma unroll 1   // keep one store per iteration — do NOT re-cluster
        for (int j = 0; j < 16; ++j) {
            // paced zero store: slot g*16+j of 64
            zdst[(g * 16 + j) * 256] = zval;

            const float4 cb = lds_cb[j * 64 + lane];
            const double bx = (double)cb.x, by = (double)cb.y,
                         bz = (double)cb.z, bw = (double)cb.w;
            const int k = j * 64 + lane;
#pragma unroll
            for (int ii = 0; ii < 4; ++ii) {
                // d' = bsq - 2*dot  (x_sq constant over k: argmin-invariant)
                const double d = fma(bw, x2[ii][3],
                                 fma(bz, x2[ii][2],
                                 fma(by, x2[ii][1],
                                 fma(bx, x2[ii][0], bsq[j]))));
                if (d < bestd[ii]) { bestd[ii] = d; bestk[ii] = k; }
            }
        }

        // Wave argmin, lexicographic (d, k), 4 rows interleaved.
        // (No stores offered here -> store queue drains under this compute.)
#pragma unroll
        for (int off = 32; off >= 1; off >>= 1) {
#pragma unroll
            for (int ii = 0; ii < 4; ++ii) {
                const double od = __shfl_xor(bestd[ii], off);
                const int    oi = __shfl_xor(bestk[ii], off);
                if (od < bestd[ii] || (od == bestd[ii] && oi < bestk[ii])) {
                    bestd[ii] = od; bestk[ii] = oi;
                }
            }
        }

#pragma unroll
        for (int ii = 0; ii < 4; ++ii) {
            const int b  = b_base + g * 4 + ii;
            const int bi = bestk[ii];
            if (lane == 0) {
                emb4[(size_t)b * C_DIM + c] = lds_cb[bi];
                idx_out[b * C_DIM + c]      = bi;   // K_ones reads it
            }
        }
    }
}

// ---------------------------------------------------------------------------
// K_ones: scatter the 131072 ones. One thread per (b*C+c) row.
// Runs after K_fused (kernel boundary orders the zero-fill and idx writes).
// ---------------------------------------------------------------------------
__global__ __launch_bounds__(256) void vq_scatter_ones(
    const int* __restrict__ idx_in,      // (B, C) flat
    float* __restrict__ out)             // one_hot at EMBED_ELEMS
{
    const int r = blockIdx.x * 256 + threadIdx.x;   // flat row, coalesced idx
    const int k = idx_in[r];
    out[EMBED_ELEMS + (size_t)r * K_DIM + k] = 1.0f;
}

extern "C" void kernel_launch(void* const* d_in, const int* in_sizes, int n_in,
                              void* d_out, int out_size, void* d_ws, size_t ws_size,
                              hipStream_t stream) {
    const float* cw_q     = (const float*)d_in[0];
    const float* codebook = (const float*)d_in[1];
    float* out = (float*)d_out;
    int*   idx = (int*)d_ws;   // 512 KB scratch

    vq_fused_kernel<<<2048, 256, 0, stream>>>(cw_q, codebook, out, idx);
    vq_scatter_ones<<<NROWS / 256, 256, 0, stream>>>(idx, out);
}

// Round 22
// 119.672 us; speedup vs baseline: 2.5486x; 1.0965x over previous
//
#include <hip/hip_runtime.h>

// Problem shapes (fixed by reference setup_inputs)
#define B_DIM 1024
#define C_DIM 128
#define K_DIM 1024
#define E_DIM 4
#define EMBED_ELEMS (B_DIM * C_DIM * E_DIM)
#define NROWS (B_DIM * C_DIM)

typedef float f32x4 __attribute__((ext_vector_type(4)));

// d_ws layout: idx[NROWS] at offset 0 (every element written every call).
// ---------------------------------------------------------------------------
// K_fused: exact-f64 argmin (R3-proven ordering) + embed/idx + paced zero
// fill, single resident cohort (2048 blocks = 8/CU, 256 KB slab each).
// R22 delta: zero stores are NON-TEMPORAL (bypass L2 write-allocate; the
// 512 MB stream goes straight to HBM, L2 stays hot for codebook/x reads).
// ---------------------------------------------------------------------------
__global__ __launch_bounds__(256) void vq_fused_kernel(
    const float* __restrict__ cw_q,      // (B, C*E) f32
    const float* __restrict__ codebook,  // (C, K, E) f32
    float* __restrict__ out,             // [embed | one_hot]
    int* __restrict__ idx_out)           // (B, C) int32 in d_ws
{
    __shared__ float4 lds_cb[K_DIM];     // 16 KB: codebook[c]

    const int lane = threadIdx.x & 63;
    const int wave = threadIdx.x >> 6;
    const int bid  = blockIdx.x;
    const int c      = bid >> 4;         // 16 blocks per c
    const int btile  = bid & 15;
    const int b_base = btile * 64 + wave * 16;

    const float4* cb4 = (const float4*)codebook + (size_t)c * K_DIM;
    const float4* x4  = (const float4*)cw_q;    // (B, C) float4
    float4* emb4 = (float4*)out;                // (B, C) float4

    // Zero-fill destination: 256 KB contiguous slab per block.
    f32x4* zdst = (f32x4*)(out + EMBED_ELEMS) + (size_t)bid * 16384
                + threadIdx.x;
    const f32x4 zval = {0.f, 0.f, 0.f, 0.f};

    // Stage codebook into LDS (once per block for 64 rows).
    for (int t = threadIdx.x; t < K_DIM; t += 256)
        lds_cb[t] = cb4[t];
    __syncthreads();

    // ||b_k||^2 in f64 (exact from f32 inputs -> true ordering, R3-proven).
    double bsq[16];
#pragma unroll
    for (int j = 0; j < 16; ++j) {
        const float4 cb = lds_cb[j * 64 + lane];
        const double bx = (double)cb.x, by = (double)cb.y,
                     bz = (double)cb.z, bw = (double)cb.w;
        bsq[j] = bx * bx + by * by + bz * bz + bw * bw;
    }

    // 4 groups of 4 rows; one paced nt zero store per j-iteration (64 slots).
    for (int g = 0; g < 4; ++g) {
        double x2[4][4];
#pragma unroll
        for (int ii = 0; ii < 4; ++ii) {
            const float4 x = x4[(size_t)(b_base + g * 4 + ii) * C_DIM + c];
            x2[ii][0] = -2.0 * (double)x.x;
            x2[ii][1] = -2.0 * (double)x.y;
            x2[ii][2] = -2.0 * (double)x.z;
            x2[ii][3] = -2.0 * (double)x.w;
        }

        double bestd[4];
        int    bestk[4];
#pragma unroll
        for (int ii = 0; ii < 4; ++ii) { bestd[ii] = INFINITY; bestk[ii] = 0x7fffffff; }

#pragma unroll 1   // keep one store per iteration — do NOT re-cluster
        for (int j = 0; j < 16; ++j) {
            // paced NON-TEMPORAL zero store: slot g*16+j of 64
            __builtin_nontemporal_store(zval, &zdst[(g * 16 + j) * 256]);

            const float4 cb = lds_cb[j * 64 + lane];
            const double bx = (double)cb.x, by = (double)cb.y,
                         bz = (double)cb.z, bw = (double)cb.w;
            const int k = j * 64 + lane;
#pragma unroll
            for (int ii = 0; ii < 4; ++ii) {
                // d' = bsq - 2*dot  (x_sq constant over k: argmin-invariant)
                const double d = fma(bw, x2[ii][3],
                                 fma(bz, x2[ii][2],
                                 fma(by, x2[ii][1],
                                 fma(bx, x2[ii][0], bsq[j]))));
                if (d < bestd[ii]) { bestd[ii] = d; bestk[ii] = k; }
            }
        }

        // Wave argmin, lexicographic (d, k), 4 rows interleaved.
#pragma unroll
        for (int off = 32; off >= 1; off >>= 1) {
#pragma unroll
            for (int ii = 0; ii < 4; ++ii) {
                const double od = __shfl_xor(bestd[ii], off);
                const int    oi = __shfl_xor(bestk[ii], off);
                if (od < bestd[ii] || (od == bestd[ii] && oi < bestk[ii])) {
                    bestd[ii] = od; bestk[ii] = oi;
                }
            }
        }

#pragma unroll
        for (int ii = 0; ii < 4; ++ii) {
            const int b  = b_base + g * 4 + ii;
            const int bi = bestk[ii];
            if (lane == 0) {
                emb4[(size_t)b * C_DIM + c] = lds_cb[bi];
                idx_out[b * C_DIM + c]      = bi;   // K_ones reads it
            }
        }
    }
}

// ---------------------------------------------------------------------------
// K_ones: scatter the 131072 ones. One thread per (b*C+c) row.
// nt store: the line was zeroed by K_fused and won't be re-read before HBM.
// ---------------------------------------------------------------------------
__global__ __launch_bounds__(256) void vq_scatter_ones(
    const int* __restrict__ idx_in,      // (B, C) flat
    float* __restrict__ out)             // one_hot at EMBED_ELEMS
{
    const int r = blockIdx.x * 256 + threadIdx.x;   // flat row, coalesced idx
    const int k = idx_in[r];
    __builtin_nontemporal_store(1.0f, &out[EMBED_ELEMS + (size_t)r * K_DIM + k]);
}

extern "C" void kernel_launch(void* const* d_in, const int* in_sizes, int n_in,
                              void* d_out, int out_size, void* d_ws, size_t ws_size,
                              hipStream_t stream) {
    const float* cw_q     = (const float*)d_in[0];
    const float* codebook = (const float*)d_in[1];
    float* out = (float*)d_out;
    int*   idx = (int*)d_ws;   // 512 KB scratch

    vq_fused_kernel<<<2048, 256, 0, stream>>>(cw_q, codebook, out, idx);
    vq_scatter_ones<<<NROWS / 256, 256, 0, stream>>>(idx, out);
}